// Round 3
// baseline (2490.918 us; speedup 1.0000x reference)
//
#include <hip/hip_runtime.h>

// WindowAttentionBlock: B=4096 windows, N=49 tokens, D=384, H=12 heads, hd=32.
// Fused per-window kernel: QKV proj -> scores -> softmax -> PV -> out proj,
// bf16 MFMA 16x16x32, fp32 accumulate. Zero HBM intermediates.
// Input/output dtype (fp32 vs bf16) is detected on-device from x's bit
// patterns (g_dt: 0=bf16, 1=fp32); all dtype branches are wave-uniform.

#define NWIN   4096
#define NTOK   49
#define DMODEL 384
#define NH     12
#define HD     32
#define XPITCH 392   // x/O row pitch in shorts (384+8)
#define QPITCH 40    // Q/K row pitch (32+8)
#define VPITCH 72    // Vt and W row pitch (64+8)
#define SCALE  2.9802322387695312e-08f   // (32)^-5, faithful to reference
#define NEGBIG -30000.0f

typedef __attribute__((ext_vector_type(8))) short short8;
typedef __attribute__((ext_vector_type(4))) short short4v;
typedef __attribute__((ext_vector_type(4))) float float4v;

__device__ __align__(16) unsigned short g_wT[4 * DMODEL * DMODEL];  // wT[m][n][k]
__device__ int g_dt;   // 0 = bf16 tensors, 1 = fp32 tensors

__device__ __forceinline__ float b2f(unsigned short h) {
  union { unsigned u; float f; } t; t.u = ((unsigned)h) << 16; return t.f;
}
__device__ __forceinline__ unsigned short f2b(float f) {
  union { float f; unsigned u; } t; t.f = f;
  return (unsigned short)((t.u + 0x7fffu + ((t.u >> 16) & 1u)) >> 16);
}

// Dtype sniff: even-indexed shorts of x are bf16 values (sane exponents near
// 127) if bf16, or fp32 mantissa low-halves (uniform random exponent field) if
// fp32. Count sane exponents over 2048 samples: bf16 -> ~2048, fp32 -> ~310.
__global__ void detect_dtype(const unsigned short* __restrict__ x) {
  __shared__ int cnt;
  if (threadIdx.x == 0) cnt = 0;
  __syncthreads();
  int local = 0;
  for (int i = threadIdx.x; i < 2048; i += 256) {
    unsigned short h = x[2 * i];
    int e = (h >> 7) & 0xFF;
    if (e >= 0x6A && e <= 0x90) local++;   // |v| in [2^-21, 2^17]
  }
  atomicAdd(&cnt, local);
  __syncthreads();
  if (threadIdx.x == 0) g_dt = (cnt < 1024) ? 1 : 0;
}

// Prep: wT[m][n][k] = W_m[k][n], converted to bf16.
__global__ void transpose_w(const void* __restrict__ Wq,
                            const void* __restrict__ Wk,
                            const void* __restrict__ Wv,
                            const void* __restrict__ Wp) {
  int idx = blockIdx.x * 256 + threadIdx.x;          // 0 .. 4*384*384-1 exactly
  int m = idx / (DMODEL * DMODEL);
  int r = idx - m * (DMODEL * DMODEL);
  int n = r / DMODEL;
  int k = r - n * DMODEL;
  const void* W = (m == 0) ? Wq : (m == 1) ? Wk : (m == 2) ? Wv : Wp;
  unsigned short v;
  if (g_dt) v = f2b(((const float*)W)[k * DMODEL + n]);
  else      v = ((const unsigned short*)W)[k * DMODEL + n];
  g_wT[idx] = v;
}

// LDS layout (shorts):
//   [0, 19208)        x window [49][XPITCH] (bf16); reused as O after head loop
//   [19208, 21168)    sQ [49][QPITCH]
//   [21168, 23128)    sK [49][QPITCH]
//   [23128, 25432)    sV Vt [32][VPITCH] (token dim padded to 64, zeros >=49)
//   [25432, 28960)    sW W  [49][VPITCH] (softmax weights, wave-local rows)
// Total 28960 shorts = 57,920 B (<= 64 KB/WG).
__global__ __launch_bounds__(256, 2)
void win_attn(const void* __restrict__ xg_,
              const void* __restrict__ maskg_,
              const void* __restrict__ bqg_,
              const void* __restrict__ bkg_,
              const void* __restrict__ bvg_,
              const void* __restrict__ bpg_,
              void* __restrict__ outg_)
{
  __shared__ __align__(16) short lds[28960];
  const int dt   = g_dt;           // uniform across grid
  const int win  = blockIdx.x;
  const int tid  = threadIdx.x;
  const int wv   = tid >> 6;       // wave 0..3 = M-band owner
  const int lane = tid & 63;
  const int c    = lane & 15;      // col-within-16 (C/D col; A/B "16"-dim index)
  const int qd   = lane >> 4;      // quad: A/B k-offset qd*8; C/D row qd*4+r

  // ---- zero-init attention scratch (any stray read -> 0.0, never NaN) ----
  {
    unsigned* z = (unsigned*)&lds[19208];            // 9752 shorts = 4876 uints
    for (int i = tid; i < 4876; i += 256) z[i] = 0u;
  }

  // ---- stage x window into LDS as bf16 (padded pitch) ----
  if (dt == 0) {
    const uint4* src = (const uint4*)((const unsigned short*)xg_ + (size_t)win * (NTOK * DMODEL));
    for (int i = tid; i < (NTOK * DMODEL) / 8; i += 256) {
      int row = i / 48, col = i - row * 48;          // 48 uint4 per 384-short row
      *(uint4*)&lds[row * XPITCH + col * 8] = src[i];
    }
  } else {
    const float4* src = (const float4*)((const float*)xg_ + (size_t)win * (NTOK * DMODEL));
    for (int i = tid; i < (NTOK * DMODEL) / 4; i += 256) {
      int row = i / 96, colq = i - row * 96;         // 96 float4 per 384-float row
      float4 f = src[i];
      short4v p;
      p[0] = (short)f2b(f.x); p[1] = (short)f2b(f.y);
      p[2] = (short)f2b(f.z); p[3] = (short)f2b(f.w);
      *(short4v*)&lds[row * XPITCH + colq * 4] = p;
    }
  }

  short* const sQ = lds + 19208;
  short* const sK = lds + 21168;
  short* const sV = lds + 23128;
  short* const sW = lds + 25432;

  // A-fragment row for this wave's band (clamped; rows >=49 are discarded dups)
  const int arow = (wv * 16 + c < NTOK) ? (wv * 16 + c) : (NTOK - 1);

  // Mask additions for this wave's 16 score rows (reused by all heads).
  float madd[4][4];
  #pragma unroll
  for (int r = 0; r < 4; ++r) {
    int m = wv * 16 + qd * 4 + r;
    #pragma unroll
    for (int nt = 0; nt < 4; ++nt) {
      int n = nt * 16 + c;
      float v;
      if (n < NTOK) {
        if (m < NTOK) {
          size_t off = (size_t)win * (NTOK * NTOK) + m * NTOK + n;
          v = dt ? ((const float*)maskg_)[off] : b2f(((const unsigned short*)maskg_)[off]);
        } else v = 0.f;
      } else v = NEGBIG;    // kill padded K columns
      madd[r][nt] = v;
    }
  }

  __syncthreads();   // x staged + scratch zeroed

  const float4v z4 = {0.f, 0.f, 0.f, 0.f};
  unsigned opack[NH][2][2];   // deferred per-head O tiles, bf16-packed (48 VGPRs)

  #pragma unroll
  for (int h = 0; h < NH; ++h) {
    // ---- QKV projection: this wave's 16-row band, 2 col tiles per matrix ----
    float4v aQ[2] = {z4, z4}, aK[2] = {z4, z4}, aV[2] = {z4, z4};
    #pragma unroll
    for (int ks = 0; ks < 12; ++ks) {
      short8 a = *(const short8*)&lds[arow * XPITCH + ks * 32 + qd * 8];
      #pragma unroll
      for (int nt = 0; nt < 2; ++nt) {
        const int colbase = (h * 32 + nt * 16 + c) * DMODEL + ks * 32 + qd * 8;
        short8 b0 = *(const short8*)&g_wT[colbase];            // WqT
        short8 b1 = *(const short8*)&g_wT[147456 + colbase];   // WkT
        short8 b2 = *(const short8*)&g_wT[294912 + colbase];   // WvT
        aQ[nt] = __builtin_amdgcn_mfma_f32_16x16x32_bf16(a, b0, aQ[nt], 0, 0, 0);
        aK[nt] = __builtin_amdgcn_mfma_f32_16x16x32_bf16(a, b1, aK[nt], 0, 0, 0);
        aV[nt] = __builtin_amdgcn_mfma_f32_16x16x32_bf16(a, b2, aV[nt], 0, 0, 0);
      }
    }
    // Q,K row-major [tok][hd]; V transposed [hd][tok] (tokens >=49 stay zero)
    #pragma unroll
    for (int nt = 0; nt < 2; ++nt) {
      const int col = h * 32 + nt * 16 + c;
      const float biasQ = dt ? ((const float*)bqg_)[col] : b2f(((const unsigned short*)bqg_)[col]);
      const float biasK = dt ? ((const float*)bkg_)[col] : b2f(((const unsigned short*)bkg_)[col]);
      const float biasV = dt ? ((const float*)bvg_)[col] : b2f(((const unsigned short*)bvg_)[col]);
      short4v vp;
      #pragma unroll
      for (int r = 0; r < 4; ++r) {
        int m = wv * 16 + qd * 4 + r;
        if (m < NTOK) {
          sQ[m * QPITCH + nt * 16 + c] = (short)f2b(aQ[nt][r] + biasQ);
          sK[m * QPITCH + nt * 16 + c] = (short)f2b(aK[nt][r] + biasK);
        }
        vp[r] = (short)((m < NTOK) ? f2b(aV[nt][r] + biasV) : (unsigned short)0);
      }
      *(short4v*)&sV[(nt * 16 + c) * VPITCH + wv * 16 + qd * 4] = vp;
    }
    __syncthreads();   // (1) Q,K,Vt visible to all waves

    // ---- scores: S[band][64 cols], K-dim = hd = 32 = one MFMA step ----
    float4v aS[4] = {z4, z4, z4, z4};
    {
      short8 aq = *(const short8*)&sQ[arow * QPITCH + qd * 8];
      #pragma unroll
      for (int nt = 0; nt < 4; ++nt) {
        int kr = nt * 16 + c; if (kr > NTOK - 1) kr = NTOK - 1;
        short8 bk8 = *(const short8*)&sK[kr * QPITCH + qd * 8];
        aS[nt] = __builtin_amdgcn_mfma_f32_16x16x32_bf16(aq, bk8, aS[nt], 0, 0, 0);
      }
    }

    // ---- softmax over n (row qd*4+r; cols spread over 16 lanes sharing qd) --
    #pragma unroll
    for (int r = 0; r < 4; ++r) {
      float s0 = fmaf(aS[0][r], SCALE, madd[r][0]);
      float s1 = fmaf(aS[1][r], SCALE, madd[r][1]);
      float s2 = fmaf(aS[2][r], SCALE, madd[r][2]);
      float s3 = fmaf(aS[3][r], SCALE, madd[r][3]);
      float mx = fmaxf(fmaxf(s0, s1), fmaxf(s2, s3));
      mx = fmaxf(mx, __shfl_xor(mx, 1));
      mx = fmaxf(mx, __shfl_xor(mx, 2));
      mx = fmaxf(mx, __shfl_xor(mx, 4));
      mx = fmaxf(mx, __shfl_xor(mx, 8));
      float e0 = __expf(fminf(s0 - mx, 0.f));
      float e1 = __expf(fminf(s1 - mx, 0.f));
      float e2 = __expf(fminf(s2 - mx, 0.f));
      float e3 = __expf(fminf(s3 - mx, 0.f));
      float sum = e0 + e1 + e2 + e3;
      sum += __shfl_xor(sum, 1);
      sum += __shfl_xor(sum, 2);
      sum += __shfl_xor(sum, 4);
      sum += __shfl_xor(sum, 8);
      float inv = 1.0f / sum;     // sum >= 1 always
      int m = wv * 16 + qd * 4 + r;
      if (m < NTOK) {   // W rows wave-local; sW private region -> no barrier
        sW[m * VPITCH +  0 + c] = (short)f2b(e0 * inv);
        sW[m * VPITCH + 16 + c] = (short)f2b(e1 * inv);
        sW[m * VPITCH + 32 + c] = (short)f2b(e2 * inv);
        sW[m * VPITCH + 48 + c] = (short)f2b(e3 * inv);
      }
    }

    // ---- PV: O_band = W[band][64] @ Vt[64 tok][32 hd] ----
    float4v aO[2] = {z4, z4};
    #pragma unroll
    for (int ks = 0; ks < 2; ++ks) {
      short8 aw = *(const short8*)&sW[arow * VPITCH + ks * 32 + qd * 8];
      #pragma unroll
      for (int nt = 0; nt < 2; ++nt) {
        short8 bv8 = *(const short8*)&sV[(nt * 16 + c) * VPITCH + ks * 32 + qd * 8];
        aO[nt] = __builtin_amdgcn_mfma_f32_16x16x32_bf16(aw, bv8, aO[nt], 0, 0, 0);
      }
    }
    #pragma unroll
    for (int nt = 0; nt < 2; ++nt) {
      opack[h][nt][0] = (unsigned)f2b(aO[nt][0]) | ((unsigned)f2b(aO[nt][1]) << 16);
      opack[h][nt][1] = (unsigned)f2b(aO[nt][2]) | ((unsigned)f2b(aO[nt][3]) << 16);
    }
    __syncthreads();   // (2) all reads done before next head overwrites scratch
  }

  // ---- assemble O [49][XPITCH] in the (dead) x region ----
  short* const sO = lds;
  #pragma unroll
  for (int h = 0; h < NH; ++h) {
    #pragma unroll
    for (int nt = 0; nt < 2; ++nt) {
      #pragma unroll
      for (int r = 0; r < 4; ++r) {
        int m = wv * 16 + qd * 4 + r;
        if (m < NTOK) {
          unsigned u = opack[h][nt][r >> 1];
          unsigned short hv = (r & 1) ? (unsigned short)(u >> 16)
                                      : (unsigned short)(u & 0xffffu);
          sO[m * XPITCH + h * 32 + nt * 16 + c] = (short)hv;
        }
      }
    }
  }
  __syncthreads();   // (3) O assembled

  // ---- output projection: each wave 96 cols; out = O @ Wp + bp ----
  float4v aP[4][6];
  #pragma unroll
  for (int mt = 0; mt < 4; ++mt)
    #pragma unroll
    for (int nt = 0; nt < 6; ++nt) aP[mt][nt] = z4;

  const int col0 = wv * 96;
  #pragma unroll
  for (int ks = 0; ks < 12; ++ks) {
    short8 af[4];
    #pragma unroll
    for (int mt = 0; mt < 4; ++mt) {
      int row = mt * 16 + c; if (row > NTOK - 1) row = NTOK - 1;
      af[mt] = *(const short8*)&sO[row * XPITCH + ks * 32 + qd * 8];
    }
    #pragma unroll
    for (int nt = 0; nt < 6; ++nt) {
      short8 bw = *(const short8*)&g_wT[442368 + (col0 + nt * 16 + c) * DMODEL + ks * 32 + qd * 8];
      #pragma unroll
      for (int mt = 0; mt < 4; ++mt)
        aP[mt][nt] = __builtin_amdgcn_mfma_f32_16x16x32_bf16(af[mt], bw, aP[mt][nt], 0, 0, 0);
    }
  }
  #pragma unroll
  for (int nt = 0; nt < 6; ++nt) {
    const int col = col0 + nt * 16 + c;
    const float biasP = dt ? ((const float*)bpg_)[col] : b2f(((const unsigned short*)bpg_)[col]);
    #pragma unroll
    for (int mt = 0; mt < 4; ++mt) {
      #pragma unroll
      for (int r = 0; r < 4; ++r) {
        int m = mt * 16 + qd * 4 + r;
        if (m < NTOK) {
          float v = aP[mt][nt][r] + biasP;
          size_t off = (size_t)win * (NTOK * DMODEL) + m * DMODEL + col;
          if (dt) ((float*)outg_)[off] = v;
          else    ((unsigned short*)outg_)[off] = f2b(v);
        }
      }
    }
  }
}

extern "C" void kernel_launch(void* const* d_in, const int* in_sizes, int n_in,
                              void* d_out, int out_size, void* d_ws, size_t ws_size,
                              hipStream_t stream) {
  const void* x    = d_in[0];
  const void* mask = d_in[1];
  const void* Wq   = d_in[2];
  const void* bq   = d_in[3];
  const void* Wk   = d_in[4];
  const void* bk   = d_in[5];
  const void* Wv   = d_in[6];
  const void* bv   = d_in[7];
  const void* Wp   = d_in[8];
  const void* bp   = d_in[9];

  detect_dtype<<<1, 256, 0, stream>>>((const unsigned short*)x);
  transpose_w<<<(4 * DMODEL * DMODEL) / 256, 256, 0, stream>>>(Wq, Wk, Wv, Wp);
  win_attn<<<NWIN, 256, 0, stream>>>(x, mask, bq, bk, bv, bp, d_out);
}